// Round 16
// baseline (138.239 us; speedup 1.0000x reference)
//
#include <hip/hip_runtime.h>

#define NN 256
#define DIN 32
#define DD 64
#define D2 128
#define RTOT 4096      // BB*NN rows
#define GBD 1024       // d blocks (4 rows each, 4/CU -> 16 waves/CU)
#define GBC 512        // bc blocks (256 threads, 8 rows each)
#define RPC 8          // rows per bc block
#define AST 32         // acc slot stride in floats (128 B line per channel)
#define PARTS 8        // stat accumulator partitions (cuts atomic chains 8x)
#define LSTR (512 * AST)   // floats per partition copy

typedef float f32x4 __attribute__((ext_vector_type(4)));
typedef float f32x2 __attribute__((ext_vector_type(2)));

__device__ __forceinline__ void fma4(f32x4& o, float s, const f32x4 w) {
  o[0] = fmaf(s, w[0], o[0]); o[1] = fmaf(s, w[1], o[1]);
  o[2] = fmaf(s, w[2], o[2]); o[3] = fmaf(s, w[3], o[3]);
}

// fp32 -> bf16 (RNE) and back
__device__ __forceinline__ unsigned f2b(float f) {
  unsigned u = __float_as_uint(f);
  return (u + 0x7FFFu + ((u >> 16) & 1u)) >> 16;
}
__device__ __forceinline__ float b2f(unsigned short h) {
  return __uint_as_float(((unsigned)h) << 16);
}

// x = fea @ encW + encb ; first 384 blocks zero the 3x8-partition acc region
__global__ __launch_bounds__(256) void enc_kernel(
    const float* __restrict__ fea, const float* __restrict__ W,
    const float* __restrict__ bias, float* __restrict__ x,
    float* __restrict__ accz) {
  if (blockIdx.x < 384) {    // 384*1024 = 393216 = 3*PARTS*LSTR
#pragma unroll
    for (int i = 0; i < 4; ++i)
      accz[blockIdx.x * 1024 + i * 256 + threadIdx.x] = 0.f;
  }
  int g = blockIdx.x * 256 + threadIdx.x;
  int r = g >> 6, c = g & 63;
  const float* fr = fea + r * DIN;
  float acc = bias[c];
#pragma unroll
  for (int k = 0; k < DIN; ++k) acc = fmaf(fr[k], W[k * DD + c], acc);
  x[g] = acc;
}

// bc (r14-proven): whole-batch Y in LDS as bf16; ballot agg; MLP1 global-W1.
// Stats into partition bid&7. acc slots padded by AST within each partition.
__global__ __launch_bounds__(256, 4) void bc_kernel(
    const float* __restrict__ adj, const float* __restrict__ x,
    const float* __restrict__ bondW, const float* __restrict__ epsp,
    const float* __restrict__ W1, const float* __restrict__ b1,
    const float* __restrict__ gbnp, const float* __restrict__ bbnp,
    const float* __restrict__ acc2p,   // prev layer s2 base, part 0
    int apply_bn,
    float* __restrict__ h1, float* __restrict__ acc1) {
  __shared__ unsigned short sYb[NN * DD];  // 32 KB bf16 Y; pst overlay after agg
  __shared__ float sh[RPC * DD];           // 2 KB
  __shared__ float sSB[2 * DD];            // 0.5 KB
  float* pst = (float*)sYb;                // 2*RPC*D2 floats (sYb dead then)
  const int tid = threadIdx.x, bid = blockIdx.x;
  const int lane = tid & 63, wv = tid >> 6;
  const int b = bid >> 5;              // 32 blocks per batch
  const int r0 = (bid & 31) * RPC;

  if (apply_bn && tid < DD) {
    float s = 0.f, q = 0.f;
#pragma unroll
    for (int p = 0; p < PARTS; ++p) {
      const float* ap = acc2p + p * LSTR;
      s += ap[tid * AST];
      q += ap[(64 + tid) * AST];
    }
    float mean = s * (1.f / RTOT);
    float var = fmaf(-mean, mean, q * (1.f / RTOT));
    float sc = gbnp[tid] * rsqrtf(var + 1e-5f);
    sSB[tid] = sc;
    sSB[64 + tid] = fmaf(-mean, sc, bbnp[tid]);
  }
  __syncthreads();

  const float* xb = x + (size_t)b * NN * DD;

  // ---- issue ALL global reads in one burst ----
  float a[2][4];
#pragma unroll
  for (int rr = 0; rr < 2; ++rr) {
    const float* adjr = adj + ((size_t)b * NN + r0 + wv * 2 + rr) * NN + lane;
#pragma unroll
    for (int ck = 0; ck < 4; ++ck) a[rr][ck] = adjr[ck * 64];
  }
  float xo[2];
#pragma unroll
  for (int rr = 0; rr < 2; ++rr)
    xo[rr] = xb[(size_t)(r0 + wv * 2 + rr) * DD + lane];
  f32x4 yv[16];
  {
    const f32x4* xb4 = (const f32x4*)xb;
#pragma unroll
    for (int k = 0; k < 16; ++k) yv[k] = xb4[tid + k * 256];
  }

  unsigned long long m[2][4];
#pragma unroll
  for (int rr = 0; rr < 2; ++rr)
#pragma unroll
    for (int ck = 0; ck < 4; ++ck) m[rr][ck] = __ballot(a[rr][ck] != 0.f);

  // ---- transform + store Y to LDS as bf16 (one vmcnt drain) ----
  {
    const int d0 = (tid & 15) * 4;
    f32x4 bw4 = *(const f32x4*)&bondW[d0];
    f32x4 aS = {0, 0, 0, 0}, aB = {0, 0, 0, 0};
    if (apply_bn) { aS = *(const f32x4*)&sSB[d0]; aB = *(const f32x4*)&sSB[64 + d0]; }
    uint2* sy2 = (uint2*)sYb;
#pragma unroll
    for (int k = 0; k < 16; ++k) {
      f32x4 v = yv[k];
#pragma unroll
      for (int e = 0; e < 4; ++e) {
        float t = v[e];
        if (apply_bn) t = fmaxf(fmaf(t, aS[e], aB[e]), 0.f);
        v[e] = fmaxf(t + bw4[e], 0.f);
      }
      uint2 pk;
      pk.x = f2b(v[0]) | (f2b(v[1]) << 16);
      pk.y = f2b(v[2]) | (f2b(v[3]) << 16);
      sy2[tid + k * 256] = pk;
    }
  }
  __syncthreads();

  // ---- agg: 8-batched bf16 LDS gathers ----
  {
    float S = 0.f, Bv = 0.f;
    if (apply_bn) { S = sSB[lane]; Bv = sSB[64 + lane]; }
    float epv = 1.f + epsp[0];
#pragma unroll
    for (int rr = 0; rr < 2; ++rr) {
      float av = 0.f;
#pragma unroll
      for (int ck = 0; ck < 4; ++ck) {
        unsigned long long mm = m[rr][ck];
        const unsigned short* yb = sYb + ck * 64 * DD + lane;
        while (mm) {
          unsigned short v[8]; bool hb[8];
#pragma unroll
          for (int u = 0; u < 8; ++u) {
            bool ok = mm != 0ull;
            int j = ok ? (int)__builtin_ctzll(mm) : 0;
            mm &= mm - 1;
            hb[u] = ok;
            v[u] = yb[j * DD];
          }
#pragma unroll
          for (int u = 0; u < 8; ++u) av += hb[u] ? b2f(v[u]) : 0.f;
        }
      }
      float xv = xo[rr];
      if (apply_bn) xv = fmaxf(fmaf(xv, S, Bv), 0.f);
      sh[(wv * 2 + rr) * DD + lane] = fmaf(epv, xv, av);
    }
  }
  __syncthreads();    // all sYb reads done; pst overlay safe

  // ---- MLP1: 8x128 tile, thread = 1 row x 4 cols, weights from global ----
  {
    int row = tid >> 5, c0 = (tid & 31) * 4;
    f32x4 o = *(const f32x4*)&b1[c0];
#pragma unroll 4
    for (int d = 0; d < DD; d += 4) {
      f32x4 hv = *(const f32x4*)&sh[row * DD + d];
      f32x4 w0 = *(const f32x4*)&W1[(d + 0) * D2 + c0];
      f32x4 w1 = *(const f32x4*)&W1[(d + 1) * D2 + c0];
      f32x4 w2 = *(const f32x4*)&W1[(d + 2) * D2 + c0];
      f32x4 w3 = *(const f32x4*)&W1[(d + 3) * D2 + c0];
      fma4(o, hv[0], w0); fma4(o, hv[1], w1); fma4(o, hv[2], w2); fma4(o, hv[3], w3);
    }
    *(f32x4*)&h1[(size_t)(b * NN + r0 + row) * D2 + c0] = o;
    *(f32x4*)&pst[row * D2 + c0] = o;
    *(f32x4*)&pst[RPC * D2 + row * D2 + c0] = o * o;
  }
  __syncthreads();
  if (tid < D2) {
    float s = 0.f, q = 0.f;
#pragma unroll
    for (int g = 0; g < RPC; ++g) {
      s += pst[g * D2 + tid];
      q += pst[RPC * D2 + g * D2 + tid];
    }
    float* a1 = acc1 + (bid & (PARTS - 1)) * LSTR;
    atomicAdd(a1 + tid * AST, s);
    atomicAdd(a1 + (128 + tid) * AST, q);
  }
}

// d: 1024 blocks x 4 rows, 16 waves/CU, W2 straight from global (L1/L2-hot).
// BN1 from 8-part acc; BN2 stats into partition bid&7.
__global__ __launch_bounds__(256) void d_kernel(
    const float* __restrict__ h1, const float* __restrict__ W2,
    const float* __restrict__ b2, const float* __restrict__ g1,
    const float* __restrict__ be1, float* __restrict__ h2,
    const float* __restrict__ acc1,
    float* __restrict__ acc2) {
  __shared__ float sS[D2], sB[D2];
  __shared__ float sh1[4][D2 + 2];
  __shared__ float pst[2][4][DD];
  const int tid = threadIdx.x, bid = blockIdx.x;
  const int row = tid >> 6, lane = tid & 63;

  if (tid < D2) {
    float s = 0.f, q = 0.f;
#pragma unroll
    for (int p = 0; p < PARTS; ++p) {
      const float* ap = acc1 + p * LSTR;
      s += ap[tid * AST];
      q += ap[(128 + tid) * AST];
    }
    float mean = s * (1.f / RTOT);
    float var = fmaf(-mean, mean, q * (1.f / RTOT));
    float sc = g1[tid] * rsqrtf(var + 1e-5f);
    sS[tid] = sc;
    sB[tid] = fmaf(-mean, sc, be1[tid]);
  }
  __syncthreads();
  {
    // 4 rows x 128 = 512 floats = 256 f32x2, 1 per thread
    f32x2 v = *(const f32x2*)(h1 + (size_t)bid * 512 + tid * 2);
    int r2 = tid >> 6, c = (tid * 2) & 127;
    v[0] = fmaxf(fmaf(v[0], sS[c + 0], sB[c + 0]), 0.f);
    v[1] = fmaxf(fmaf(v[1], sS[c + 1], sB[c + 1]), 0.f);
    *(f32x2*)&sh1[r2][c] = v;
  }
  __syncthreads();
  {
    // thread = (row, out-col lane): 128 pipelined coalesced W2 loads;
    // sh1[row][c] is a wave-wide broadcast (free)
    float o = b2[lane];
    const float* w = W2 + lane;
#pragma unroll 8
    for (int c = 0; c < D2; ++c)
      o = fmaf(sh1[row][c], w[c * DD], o);
    h2[(size_t)(bid * 4 + row) * DD + lane] = o;
    pst[0][row][lane] = o;
    pst[1][row][lane] = o * o;
  }
  __syncthreads();
  if (tid < DD) {
    float s = pst[0][0][tid] + pst[0][1][tid] + pst[0][2][tid] + pst[0][3][tid];
    float q = pst[1][0][tid] + pst[1][1][tid] + pst[1][2][tid] + pst[1][3][tid];
    float* a2 = acc2 + (bid & (PARTS - 1)) * LSTR;
    atomicAdd(a2 + tid * AST, s);
    atomicAdd(a2 + (64 + tid) * AST, q);
  }
}

// fin: BN2 (no relu) from 8-part acc -> out
__global__ __launch_bounds__(256) void fin_kernel(
    const float* __restrict__ h2, const float* __restrict__ gbn,
    const float* __restrict__ bbn, const float* __restrict__ acc2,
    float* __restrict__ outp) {
  __shared__ float sS2[DD], sB2[DD];
  int tid = threadIdx.x, bid = blockIdx.x;
  if (tid < 64) {
    float s = 0.f, q = 0.f;
#pragma unroll
    for (int p = 0; p < PARTS; ++p) {
      const float* ap = acc2 + p * LSTR;
      s += ap[tid * AST];
      q += ap[(64 + tid) * AST];
    }
    float mean = s * (1.f / RTOT);
    float var = fmaf(-mean, mean, q * (1.f / RTOT));
    float sc = gbn[tid] * rsqrtf(var + 1e-5f);
    sS2[tid] = sc;
    sB2[tid] = fmaf(-mean, sc, bbn[tid]);
  }
  __syncthreads();
#pragma unroll
  for (int k = 0; k < 4; ++k) {
    int idx = bid * 1024 + k * 256 + tid;
    int c = idx & 63;
    outp[idx] = fmaf(h2[idx], sS2[c], sB2[c]);
  }
}

extern "C" void kernel_launch(void* const* d_in, const int* in_sizes, int n_in,
                              void* d_out, int out_size, void* d_ws, size_t ws_size,
                              hipStream_t stream) {
  const float* fea  = (const float*)d_in[0];
  const float* adj  = (const float*)d_in[1];
  const float* encW = (const float*)d_in[2];
  const float* encb = (const float*)d_in[3];
  const float* bondW= (const float*)d_in[4];
  const float* eps  = (const float*)d_in[5];
  const float* W1   = (const float*)d_in[6];
  const float* b1   = (const float*)d_in[7];
  const float* g1   = (const float*)d_in[8];
  const float* be1  = (const float*)d_in[9];
  const float* W2   = (const float*)d_in[10];
  const float* b2   = (const float*)d_in[11];
  const float* gbn  = (const float*)d_in[12];
  const float* bbn  = (const float*)d_in[13];
  float* out = (float*)d_out;
  float* ws  = (float*)d_ws;

  float* x   = ws;                 // 262144 floats (enc out / raw h2)
  float* h1  = ws + 262144;        // 524288 floats
  float* acc = ws + 786432;        // 3 layers x PARTS x LSTR floats

  enc_kernel<<<1024, 256, 0, stream>>>(fea, encW, encb, x, acc);
  for (int l = 0; l < 3; ++l) {
    float* accl = acc + (size_t)l * PARTS * LSTR;
    bc_kernel<<<GBC, 256, 0, stream>>>(
        adj, x, bondW + l * DD, eps + l, W1 + l * DD * D2, b1 + l * D2,
        l ? gbn + (l - 1) * DD : gbn, l ? bbn + (l - 1) * DD : bbn,
        l ? acc + (size_t)(l - 1) * PARTS * LSTR + 256 * AST : acc,
        l > 0 ? 1 : 0, h1, accl);
    d_kernel<<<GBD, 256, 0, stream>>>(h1, W2 + l * D2 * DD, b2 + l * DD,
                                      g1 + l * D2, be1 + l * D2, x,
                                      accl, accl + 256 * AST);
  }
  fin_kernel<<<256, 256, 0, stream>>>(x, gbn + 2 * DD, bbn + 2 * DD,
                                      acc + (size_t)2 * PARTS * LSTR + 256 * AST, out);
}

// Round 17
// 96.944 us; speedup vs baseline: 1.4260x; 1.4260x over previous
//
#include <hip/hip_runtime.h>

#define NN 256
#define DIN 32
#define DD 64
#define D2 128
#define RTOT 4096      // BB*NN rows
#define GBD 256        // d/fin blocks
#define RPB 16         // rows per d block
#define GBC 512        // bc blocks
#define RPC 8          // rows per bc block
#define AST 32         // acc slot stride in floats (128 B line per channel)
#define PARTS 8        // stat accumulator partitions (cuts same-line chains 8x)
#define LSTR (512 * AST)   // floats per partition copy

typedef float f32x4 __attribute__((ext_vector_type(4)));
typedef float f32x2 __attribute__((ext_vector_type(2)));

__device__ __forceinline__ void fma4(f32x4& o, float s, const f32x4 w) {
  o[0] = fmaf(s, w[0], o[0]); o[1] = fmaf(s, w[1], o[1]);
  o[2] = fmaf(s, w[2], o[2]); o[3] = fmaf(s, w[3], o[3]);
}

// fp32 -> bf16 (RNE) and back
__device__ __forceinline__ unsigned f2b(float f) {
  unsigned u = __float_as_uint(f);
  return (u + 0x7FFFu + ((u >> 16) & 1u)) >> 16;
}
__device__ __forceinline__ float b2f(unsigned short h) {
  return __uint_as_float(((unsigned)h) << 16);
}

// x = fea @ encW + encb ; first 384 blocks zero the 3x8-partition acc region
__global__ __launch_bounds__(256) void enc_kernel(
    const float* __restrict__ fea, const float* __restrict__ W,
    const float* __restrict__ bias, float* __restrict__ x,
    float* __restrict__ accz) {
  if (blockIdx.x < 384) {    // 384*1024 = 393216 = 3*PARTS*LSTR
#pragma unroll
    for (int i = 0; i < 4; ++i)
      accz[blockIdx.x * 1024 + i * 256 + threadIdx.x] = 0.f;
  }
  int g = blockIdx.x * 256 + threadIdx.x;
  int r = g >> 6, c = g & 63;
  const float* fr = fea + r * DIN;
  float acc = bias[c];
#pragma unroll
  for (int k = 0; k < DIN; ++k) acc = fmaf(fr[k], W[k * DD + c], acc);
  x[g] = acc;
}

// bc (r14-proven): whole-batch Y in LDS as bf16; ballot agg; MLP1 global-W1.
// BN1 stats into partition bid&7; prev BN2 stats summed over 8 partitions.
__global__ __launch_bounds__(256, 4) void bc_kernel(
    const float* __restrict__ adj, const float* __restrict__ x,
    const float* __restrict__ bondW, const float* __restrict__ epsp,
    const float* __restrict__ W1, const float* __restrict__ b1,
    const float* __restrict__ gbnp, const float* __restrict__ bbnp,
    const float* __restrict__ acc2p,   // prev layer s2 base (partition 0)
    int apply_bn,
    float* __restrict__ h1, float* __restrict__ acc1) {
  __shared__ unsigned short sYb[NN * DD];  // 32 KB bf16 Y; pst overlay after agg
  __shared__ float sh[RPC * DD];           // 2 KB
  __shared__ float sSB[2 * DD];            // 0.5 KB
  float* pst = (float*)sYb;                // 2*RPC*D2 floats (sYb dead then)
  const int tid = threadIdx.x, bid = blockIdx.x;
  const int lane = tid & 63, wv = tid >> 6;
  const int b = bid >> 5;              // 32 blocks per batch
  const int r0 = (bid & 31) * RPC;

  if (apply_bn && tid < DD) {
    float s = 0.f, q = 0.f;
#pragma unroll
    for (int p = 0; p < PARTS; ++p) {
      const float* ap = acc2p + p * LSTR;
      s += ap[tid * AST];
      q += ap[(64 + tid) * AST];
    }
    float mean = s * (1.f / RTOT);
    float var = fmaf(-mean, mean, q * (1.f / RTOT));
    float sc = gbnp[tid] * rsqrtf(var + 1e-5f);
    sSB[tid] = sc;
    sSB[64 + tid] = fmaf(-mean, sc, bbnp[tid]);
  }
  __syncthreads();

  const float* xb = x + (size_t)b * NN * DD;

  // ---- issue ALL global reads in one burst ----
  float a[2][4];
#pragma unroll
  for (int rr = 0; rr < 2; ++rr) {
    const float* adjr = adj + ((size_t)b * NN + r0 + wv * 2 + rr) * NN + lane;
#pragma unroll
    for (int ck = 0; ck < 4; ++ck) a[rr][ck] = adjr[ck * 64];
  }
  float xo[2];
#pragma unroll
  for (int rr = 0; rr < 2; ++rr)
    xo[rr] = xb[(size_t)(r0 + wv * 2 + rr) * DD + lane];
  f32x4 yv[16];
  {
    const f32x4* xb4 = (const f32x4*)xb;
#pragma unroll
    for (int k = 0; k < 16; ++k) yv[k] = xb4[tid + k * 256];
  }

  unsigned long long m[2][4];
#pragma unroll
  for (int rr = 0; rr < 2; ++rr)
#pragma unroll
    for (int ck = 0; ck < 4; ++ck) m[rr][ck] = __ballot(a[rr][ck] != 0.f);

  // ---- transform + store Y to LDS as bf16 (one vmcnt drain) ----
  {
    const int d0 = (tid & 15) * 4;
    f32x4 bw4 = *(const f32x4*)&bondW[d0];
    f32x4 aS = {0, 0, 0, 0}, aB = {0, 0, 0, 0};
    if (apply_bn) { aS = *(const f32x4*)&sSB[d0]; aB = *(const f32x4*)&sSB[64 + d0]; }
    uint2* sy2 = (uint2*)sYb;
#pragma unroll
    for (int k = 0; k < 16; ++k) {
      f32x4 v = yv[k];
#pragma unroll
      for (int e = 0; e < 4; ++e) {
        float t = v[e];
        if (apply_bn) t = fmaxf(fmaf(t, aS[e], aB[e]), 0.f);
        v[e] = fmaxf(t + bw4[e], 0.f);
      }
      uint2 pk;
      pk.x = f2b(v[0]) | (f2b(v[1]) << 16);
      pk.y = f2b(v[2]) | (f2b(v[3]) << 16);
      sy2[tid + k * 256] = pk;
    }
  }
  __syncthreads();

  // ---- agg: 8-batched bf16 LDS gathers ----
  {
    float S = 0.f, Bv = 0.f;
    if (apply_bn) { S = sSB[lane]; Bv = sSB[64 + lane]; }
    float epv = 1.f + epsp[0];
#pragma unroll
    for (int rr = 0; rr < 2; ++rr) {
      float av = 0.f;
#pragma unroll
      for (int ck = 0; ck < 4; ++ck) {
        unsigned long long mm = m[rr][ck];
        const unsigned short* yb = sYb + ck * 64 * DD + lane;
        while (mm) {
          unsigned short v[8]; bool hb[8];
#pragma unroll
          for (int u = 0; u < 8; ++u) {
            bool ok = mm != 0ull;
            int j = ok ? (int)__builtin_ctzll(mm) : 0;
            mm &= mm - 1;
            hb[u] = ok;
            v[u] = yb[j * DD];
          }
#pragma unroll
          for (int u = 0; u < 8; ++u) av += hb[u] ? b2f(v[u]) : 0.f;
        }
      }
      float xv = xo[rr];
      if (apply_bn) xv = fmaxf(fmaf(xv, S, Bv), 0.f);
      sh[(wv * 2 + rr) * DD + lane] = fmaf(epv, xv, av);
    }
  }
  __syncthreads();    // all sYb reads done; pst overlay safe

  // ---- MLP1: 8x128 tile, thread = 1 row x 4 cols, weights from global ----
  {
    int row = tid >> 5, c0 = (tid & 31) * 4;
    f32x4 o = *(const f32x4*)&b1[c0];
#pragma unroll 4
    for (int d = 0; d < DD; d += 4) {
      f32x4 hv = *(const f32x4*)&sh[row * DD + d];
      f32x4 w0 = *(const f32x4*)&W1[(d + 0) * D2 + c0];
      f32x4 w1 = *(const f32x4*)&W1[(d + 1) * D2 + c0];
      f32x4 w2 = *(const f32x4*)&W1[(d + 2) * D2 + c0];
      f32x4 w3 = *(const f32x4*)&W1[(d + 3) * D2 + c0];
      fma4(o, hv[0], w0); fma4(o, hv[1], w1); fma4(o, hv[2], w2); fma4(o, hv[3], w3);
    }
    *(f32x4*)&h1[(size_t)(b * NN + r0 + row) * D2 + c0] = o;
    *(f32x4*)&pst[row * D2 + c0] = o;
    *(f32x4*)&pst[RPC * D2 + row * D2 + c0] = o * o;
  }
  __syncthreads();
  if (tid < D2) {
    float s = 0.f, q = 0.f;
#pragma unroll
    for (int g = 0; g < RPC; ++g) {
      s += pst[g * D2 + tid];
      q += pst[RPC * D2 + g * D2 + tid];
    }
    float* a1 = acc1 + (bid & (PARTS - 1)) * LSTR;
    atomicAdd(a1 + tid * AST, s);
    atomicAdd(a1 + (128 + tid) * AST, q);
  }
}

// d (r14-proven shape: 256 blocks x 16 rows, LDS W2): BN1 from 8-part acc +
// ReLU + MLP2 -> raw h2 (into x) + BN2 stats into partition bid&7.
__global__ __launch_bounds__(256) void d_kernel(
    const float* __restrict__ h1, const float* __restrict__ W2,
    const float* __restrict__ b2, const float* __restrict__ g1,
    const float* __restrict__ be1, float* __restrict__ h2,
    const float* __restrict__ acc1,
    float* __restrict__ acc2) {
  __shared__ float sW2[D2 * DD];          // 32 KB
  __shared__ float sh1[RPB][D2 + 4];
  __shared__ float sS[D2], sB[D2];
  __shared__ float pst[2 * 8 * DD];       // 4 KB
  int tid = threadIdx.x, bid = blockIdx.x;

  {
    const f32x4* w4 = (const f32x4*)W2;
    f32x4* s4 = (f32x4*)sW2;
#pragma unroll
    for (int i = 0; i < 8; ++i) s4[tid + i * 256] = w4[tid + i * 256];
  }
  if (tid < D2) {
    float s = 0.f, q = 0.f;
#pragma unroll
    for (int p = 0; p < PARTS; ++p) {
      const float* ap = acc1 + p * LSTR;
      s += ap[tid * AST];
      q += ap[(128 + tid) * AST];
    }
    float mean = s * (1.f / RTOT);
    float var = fmaf(-mean, mean, q * (1.f / RTOT));
    float sc = g1[tid] * rsqrtf(var + 1e-5f);
    sS[tid] = sc;
    sB[tid] = fmaf(-mean, sc, be1[tid]);
  }
  __syncthreads();
  {
    const f32x4* h14 = (const f32x4*)(h1 + (size_t)bid * RPB * D2);
#pragma unroll
    for (int ii = 0; ii < 2; ++ii) {
      int i = tid + ii * 256;
      f32x4 v = h14[i];
      int lr = i >> 5, c = (i & 31) * 4;
      v[0] = fmaxf(fmaf(v[0], sS[c + 0], sB[c + 0]), 0.f);
      v[1] = fmaxf(fmaf(v[1], sS[c + 1], sB[c + 1]), 0.f);
      v[2] = fmaxf(fmaf(v[2], sS[c + 2], sB[c + 2]), 0.f);
      v[3] = fmaxf(fmaf(v[3], sS[c + 3], sB[c + 3]), 0.f);
      *(f32x4*)&sh1[lr][c] = v;
    }
  }
  __syncthreads();

  // MLP2: 16x64 tile; 128 threads, each 2 rows x 4 cols
  float* pssum = pst;
  float* pssq  = pst + 8 * DD;
  if (tid < 128) {
    int rg = tid >> 4;
    int c0 = (tid & 15) * 4;
    f32x4 bv = *(const f32x4*)&b2[c0];
    f32x4 o0 = bv, o1 = bv;
    for (int c = 0; c < D2; c += 4) {
      f32x4 s0 = *(const f32x4*)&sh1[rg * 2 + 0][c];
      f32x4 s1 = *(const f32x4*)&sh1[rg * 2 + 1][c];
      f32x4 w0 = *(const f32x4*)&sW2[(c + 0) * DD + c0];
      f32x4 w1 = *(const f32x4*)&sW2[(c + 1) * DD + c0];
      f32x4 w2 = *(const f32x4*)&sW2[(c + 2) * DD + c0];
      f32x4 w3 = *(const f32x4*)&sW2[(c + 3) * DD + c0];
      fma4(o0, s0[0], w0); fma4(o0, s0[1], w1); fma4(o0, s0[2], w2); fma4(o0, s0[3], w3);
      fma4(o1, s1[0], w0); fma4(o1, s1[1], w1); fma4(o1, s1[2], w2); fma4(o1, s1[3], w3);
    }
    size_t gr = (size_t)(bid * RPB + rg * 2) * DD + c0;
    *(f32x4*)&h2[gr] = o0;
    *(f32x4*)&h2[gr + DD] = o1;
    *(f32x4*)&pssum[rg * DD + c0] = o0 + o1;
    *(f32x4*)&pssq[rg * DD + c0] = o0 * o0 + o1 * o1;
  }
  __syncthreads();
  if (tid < DD) {
    float s = 0.f, q = 0.f;
#pragma unroll
    for (int g = 0; g < 8; ++g) { s += pssum[g * DD + tid]; q += pssq[g * DD + tid]; }
    float* a2 = acc2 + (bid & (PARTS - 1)) * LSTR;
    atomicAdd(a2 + tid * AST, s);
    atomicAdd(a2 + (64 + tid) * AST, q);
  }
}

// fin: BN2 (no relu) from 8-part acc -> out
__global__ __launch_bounds__(256) void fin_kernel(
    const float* __restrict__ h2, const float* __restrict__ gbn,
    const float* __restrict__ bbn, const float* __restrict__ acc2,
    float* __restrict__ outp) {
  __shared__ float sS2[DD], sB2[DD];
  int tid = threadIdx.x, bid = blockIdx.x;
  if (tid < 64) {
    float s = 0.f, q = 0.f;
#pragma unroll
    for (int p = 0; p < PARTS; ++p) {
      const float* ap = acc2 + p * LSTR;
      s += ap[tid * AST];
      q += ap[(64 + tid) * AST];
    }
    float mean = s * (1.f / RTOT);
    float var = fmaf(-mean, mean, q * (1.f / RTOT));
    float sc = gbn[tid] * rsqrtf(var + 1e-5f);
    sS2[tid] = sc;
    sB2[tid] = fmaf(-mean, sc, bbn[tid]);
  }
  __syncthreads();
#pragma unroll
  for (int k = 0; k < 4; ++k) {
    int idx = bid * 1024 + k * 256 + tid;
    int c = idx & 63;
    outp[idx] = fmaf(h2[idx], sS2[c], sB2[c]);
  }
}

extern "C" void kernel_launch(void* const* d_in, const int* in_sizes, int n_in,
                              void* d_out, int out_size, void* d_ws, size_t ws_size,
                              hipStream_t stream) {
  const float* fea  = (const float*)d_in[0];
  const float* adj  = (const float*)d_in[1];
  const float* encW = (const float*)d_in[2];
  const float* encb = (const float*)d_in[3];
  const float* bondW= (const float*)d_in[4];
  const float* eps  = (const float*)d_in[5];
  const float* W1   = (const float*)d_in[6];
  const float* b1   = (const float*)d_in[7];
  const float* g1   = (const float*)d_in[8];
  const float* be1  = (const float*)d_in[9];
  const float* W2   = (const float*)d_in[10];
  const float* b2   = (const float*)d_in[11];
  const float* gbn  = (const float*)d_in[12];
  const float* bbn  = (const float*)d_in[13];
  float* out = (float*)d_out;
  float* ws  = (float*)d_ws;

  float* x   = ws;                 // 262144 floats (enc out / raw h2)
  float* h1  = ws + 262144;        // 524288 floats
  float* acc = ws + 786432;        // 3 layers x PARTS x LSTR floats

  enc_kernel<<<1024, 256, 0, stream>>>(fea, encW, encb, x, acc);
  for (int l = 0; l < 3; ++l) {
    float* accl = acc + (size_t)l * PARTS * LSTR;
    bc_kernel<<<GBC, 256, 0, stream>>>(
        adj, x, bondW + l * DD, eps + l, W1 + l * DD * D2, b1 + l * D2,
        l ? gbn + (l - 1) * DD : gbn, l ? bbn + (l - 1) * DD : bbn,
        l ? acc + (size_t)(l - 1) * PARTS * LSTR + 256 * AST : acc,
        l > 0 ? 1 : 0, h1, accl);
    d_kernel<<<GBD, 256, 0, stream>>>(h1, W2 + l * D2 * DD, b2 + l * DD,
                                      g1 + l * D2, be1 + l * D2, x,
                                      accl, accl + 256 * AST);
  }
  fin_kernel<<<256, 256, 0, stream>>>(x, gbn + 2 * DD, bbn + 2 * DD,
                                      acc + (size_t)2 * PARTS * LSTR + 256 * AST, out);
}

// Round 18
// 86.967 us; speedup vs baseline: 1.5896x; 1.1147x over previous
//
#include <hip/hip_runtime.h>

#define NN 256
#define DIN 32
#define DD 64
#define D2 128
#define RTOT 4096      // BB*NN rows
#define GBD 256        // d/fin blocks
#define RPB 16         // rows per d block
#define GBC 512        // bc blocks
#define RPC 8          // rows per bc block
#define AST 32         // acc slot stride in floats (128 B line per channel)

typedef float f32x4 __attribute__((ext_vector_type(4)));
typedef float f32x2 __attribute__((ext_vector_type(2)));

__device__ __forceinline__ void fma4(f32x4& o, float s, const f32x4 w) {
  o[0] = fmaf(s, w[0], o[0]); o[1] = fmaf(s, w[1], o[1]);
  o[2] = fmaf(s, w[2], o[2]); o[3] = fmaf(s, w[3], o[3]);
}

// fp32 -> bf16 (RNE) and back
__device__ __forceinline__ unsigned f2b(float f) {
  unsigned u = __float_as_uint(f);
  return (u + 0x7FFFu + ((u >> 16) & 1u)) >> 16;
}
__device__ __forceinline__ float b2f(unsigned short h) {
  return __uint_as_float(((unsigned)h) << 16);
}

// x(bf16) = fea @ encW + encb ; first 48 blocks zero the acc region
__global__ __launch_bounds__(256) void enc_kernel(
    const float* __restrict__ fea, const float* __restrict__ W,
    const float* __restrict__ bias, unsigned short* __restrict__ xb16,
    float* __restrict__ accz) {
  if (blockIdx.x < 48) {     // 48*1024 = 49152 = 3*512*AST
#pragma unroll
    for (int i = 0; i < 4; ++i)
      accz[blockIdx.x * 1024 + i * 256 + threadIdx.x] = 0.f;
  }
  int g = blockIdx.x * 256 + threadIdx.x;   // 512 blocks, 2 elems/thread
  int r = g >> 5, c0 = (g & 31) * 2;
  const float* fr = fea + r * DIN;
  float a0 = bias[c0], a1 = bias[c0 + 1];
#pragma unroll
  for (int k = 0; k < DIN; ++k) {
    float fv = fr[k];
    a0 = fmaf(fv, W[k * DD + c0], a0);
    a1 = fmaf(fv, W[k * DD + c0 + 1], a1);
  }
  ((unsigned*)xb16)[g] = f2b(a0) | (f2b(a1) << 16);
}

// bc: whole-batch Y (from bf16 x) staged in LDS as bf16; ballot agg;
// MLP1 global-W1 -> h1 (bf16); fp32 BN1 stats via padded atomics.
// XCD-affinity swizzle: all 32 blocks of a batch land on one XCD.
__global__ __launch_bounds__(256, 4) void bc_kernel(
    const float* __restrict__ adj, const unsigned short* __restrict__ xb16,
    const float* __restrict__ bondW, const float* __restrict__ epsp,
    const float* __restrict__ W1, const float* __restrict__ b1,
    const float* __restrict__ gbnp, const float* __restrict__ bbnp,
    const float* __restrict__ acc2p,   // prev layer s2 base (padded)
    int apply_bn,
    unsigned short* __restrict__ h1b, float* __restrict__ acc1) {
  __shared__ unsigned short sYb[NN * DD];  // 32 KB bf16 Y; pst overlay after agg
  __shared__ float sh[RPC * DD];           // 2 KB
  __shared__ float sSB[2 * DD];            // 0.5 KB
  float* pst = (float*)sYb;                // 2*RPC*D2 floats (sYb dead then)
  const int tid = threadIdx.x;
  const int sbid = ((blockIdx.x & 7) << 6) + (blockIdx.x >> 3);  // XCD affinity
  const int lane = tid & 63, wv = tid >> 6;
  const int b = sbid >> 5;             // 32 blocks per batch -> same XCD
  const int r0 = (sbid & 31) * RPC;

  if (apply_bn && tid < DD) {
    float s = acc2p[tid * AST], q = acc2p[(64 + tid) * AST];
    float mean = s * (1.f / RTOT);
    float var = fmaf(-mean, mean, q * (1.f / RTOT));
    float sc = gbnp[tid] * rsqrtf(var + 1e-5f);
    sSB[tid] = sc;
    sSB[64 + tid] = fmaf(-mean, sc, bbnp[tid]);
  }
  __syncthreads();

  const unsigned short* xb = xb16 + (size_t)b * NN * DD;

  // ---- issue ALL global reads in one burst ----
  float a[2][4];
#pragma unroll
  for (int rr = 0; rr < 2; ++rr) {
    const float* adjr = adj + ((size_t)b * NN + r0 + wv * 2 + rr) * NN + lane;
#pragma unroll
    for (int ck = 0; ck < 4; ++ck) a[rr][ck] = adjr[ck * 64];
  }
  unsigned short xo[2];
#pragma unroll
  for (int rr = 0; rr < 2; ++rr)
    xo[rr] = xb[(size_t)(r0 + wv * 2 + rr) * DD + lane];
  uint4 yv[8];                          // 8 x 16B = whole batch bf16 / 256 thr
  {
    const uint4* xb4 = (const uint4*)xb;
#pragma unroll
    for (int k = 0; k < 8; ++k) yv[k] = xb4[tid + k * 256];
  }

  unsigned long long m[2][4];
#pragma unroll
  for (int rr = 0; rr < 2; ++rr)
#pragma unroll
    for (int ck = 0; ck < 4; ++ck) m[rr][ck] = __ballot(a[rr][ck] != 0.f);

  // ---- transform + store Y to LDS as bf16 (one vmcnt drain) ----
  {
    const int d0 = (tid & 7) * 8;       // this thread's 8-channel group
    float BW8[8], S8[8], B8[8];
#pragma unroll
    for (int j = 0; j < 8; ++j) {
      BW8[j] = bondW[d0 + j];
      S8[j] = apply_bn ? sSB[d0 + j] : 0.f;
      B8[j] = apply_bn ? sSB[64 + d0 + j] : 0.f;
    }
    uint4* sy4 = (uint4*)sYb;
#pragma unroll
    for (int k = 0; k < 8; ++k) {
      unsigned w[4] = {yv[k].x, yv[k].y, yv[k].z, yv[k].w};
      unsigned o[4];
#pragma unroll
      for (int q = 0; q < 4; ++q) {
        float f0 = __uint_as_float(w[q] << 16);
        float f1 = __uint_as_float(w[q] & 0xFFFF0000u);
        if (apply_bn) {
          f0 = fmaxf(fmaf(f0, S8[2 * q], B8[2 * q]), 0.f);
          f1 = fmaxf(fmaf(f1, S8[2 * q + 1], B8[2 * q + 1]), 0.f);
        }
        f0 = fmaxf(f0 + BW8[2 * q], 0.f);
        f1 = fmaxf(f1 + BW8[2 * q + 1], 0.f);
        o[q] = f2b(f0) | (f2b(f1) << 16);
      }
      sy4[tid + k * 256] = make_uint4(o[0], o[1], o[2], o[3]);
    }
  }
  __syncthreads();

  // ---- agg: 8-batched bf16 LDS gathers ----
  {
    float S = 0.f, Bv = 0.f;
    if (apply_bn) { S = sSB[lane]; Bv = sSB[64 + lane]; }
    float epv = 1.f + epsp[0];
#pragma unroll
    for (int rr = 0; rr < 2; ++rr) {
      float av = 0.f;
#pragma unroll
      for (int ck = 0; ck < 4; ++ck) {
        unsigned long long mm = m[rr][ck];
        const unsigned short* yb = sYb + ck * 64 * DD + lane;
        while (mm) {
          unsigned short v[8]; bool hb[8];
#pragma unroll
          for (int u = 0; u < 8; ++u) {
            bool ok = mm != 0ull;
            int j = ok ? (int)__builtin_ctzll(mm) : 0;
            mm &= mm - 1;
            hb[u] = ok;
            v[u] = yb[j * DD];
          }
#pragma unroll
          for (int u = 0; u < 8; ++u) av += hb[u] ? b2f(v[u]) : 0.f;
        }
      }
      float xv = b2f(xo[rr]);
      if (apply_bn) xv = fmaxf(fmaf(xv, S, Bv), 0.f);
      sh[(wv * 2 + rr) * DD + lane] = fmaf(epv, xv, av);
    }
  }
  __syncthreads();    // all sYb reads done; pst overlay safe

  // ---- MLP1: 8x128 tile, thread = 1 row x 4 cols, weights from global ----
  {
    int row = tid >> 5, c0 = (tid & 31) * 4;
    f32x4 o = *(const f32x4*)&b1[c0];
#pragma unroll 4
    for (int d = 0; d < DD; d += 4) {
      f32x4 hv = *(const f32x4*)&sh[row * DD + d];
      f32x4 w0 = *(const f32x4*)&W1[(d + 0) * D2 + c0];
      f32x4 w1 = *(const f32x4*)&W1[(d + 1) * D2 + c0];
      f32x4 w2 = *(const f32x4*)&W1[(d + 2) * D2 + c0];
      f32x4 w3 = *(const f32x4*)&W1[(d + 3) * D2 + c0];
      fma4(o, hv[0], w0); fma4(o, hv[1], w1); fma4(o, hv[2], w2); fma4(o, hv[3], w3);
    }
    uint2 hp;
    hp.x = f2b(o[0]) | (f2b(o[1]) << 16);
    hp.y = f2b(o[2]) | (f2b(o[3]) << 16);
    *(uint2*)&h1b[(size_t)(b * NN + r0 + row) * D2 + c0] = hp;
    *(f32x4*)&pst[row * D2 + c0] = o;                    // fp32 stats
    *(f32x4*)&pst[RPC * D2 + row * D2 + c0] = o * o;
  }
  __syncthreads();
  if (tid < D2) {
    float s = 0.f, q = 0.f;
#pragma unroll
    for (int g = 0; g < RPC; ++g) {
      s += pst[g * D2 + tid];
      q += pst[RPC * D2 + g * D2 + tid];
    }
    atomicAdd(acc1 + tid * AST, s);
    atomicAdd(acc1 + (128 + tid) * AST, q);
  }
}

// d (r14 shape: 256 blocks x 16 rows, LDS W2): BN1 + ReLU + MLP2 ->
// raw h2 (bf16, into x) + padded fp32 BN2 stats.
__global__ __launch_bounds__(256) void d_kernel(
    const unsigned short* __restrict__ h1b, const float* __restrict__ W2,
    const float* __restrict__ b2, const float* __restrict__ g1,
    const float* __restrict__ be1, unsigned short* __restrict__ xb16,
    const float* __restrict__ acc1,
    float* __restrict__ acc2) {
  __shared__ float sW2[D2 * DD];          // 32 KB
  __shared__ float sh1[RPB][D2 + 4];
  __shared__ float sS[D2], sB[D2];
  __shared__ float pst[2 * 8 * DD];       // 4 KB
  int tid = threadIdx.x, bid = blockIdx.x;

  {
    const f32x4* w4 = (const f32x4*)W2;
    f32x4* s4 = (f32x4*)sW2;
#pragma unroll
    for (int i = 0; i < 8; ++i) s4[tid + i * 256] = w4[tid + i * 256];
  }
  if (tid < D2) {
    float mean = acc1[tid * AST] * (1.f / RTOT);
    float var = fmaf(-mean, mean, acc1[(128 + tid) * AST] * (1.f / RTOT));
    float sc = g1[tid] * rsqrtf(var + 1e-5f);
    sS[tid] = sc;
    sB[tid] = fmaf(-mean, sc, be1[tid]);
  }
  __syncthreads();
  {
    // 16 rows x 128 = 2048 bf16 = 1 uint4 (8 elems) per thread
    uint4 hv = ((const uint4*)(h1b + (size_t)bid * RPB * D2))[tid];
    int row = tid >> 4, cb = (tid & 15) * 8;
    unsigned w[4] = {hv.x, hv.y, hv.z, hv.w};
#pragma unroll
    for (int q = 0; q < 4; ++q) {
      float f0 = __uint_as_float(w[q] << 16);
      float f1 = __uint_as_float(w[q] & 0xFFFF0000u);
      int c = cb + 2 * q;
      sh1[row][c]     = fmaxf(fmaf(f0, sS[c],     sB[c]),     0.f);
      sh1[row][c + 1] = fmaxf(fmaf(f1, sS[c + 1], sB[c + 1]), 0.f);
    }
  }
  __syncthreads();

  // MLP2: 16x64 tile; 128 threads, each 2 rows x 4 cols
  float* pssum = pst;
  float* pssq  = pst + 8 * DD;
  if (tid < 128) {
    int rg = tid >> 4;
    int c0 = (tid & 15) * 4;
    f32x4 bv = *(const f32x4*)&b2[c0];
    f32x4 o0 = bv, o1 = bv;
    for (int c = 0; c < D2; c += 4) {
      f32x4 s0 = *(const f32x4*)&sh1[rg * 2 + 0][c];
      f32x4 s1 = *(const f32x4*)&sh1[rg * 2 + 1][c];
      f32x4 w0 = *(const f32x4*)&sW2[(c + 0) * DD + c0];
      f32x4 w1 = *(const f32x4*)&sW2[(c + 1) * DD + c0];
      f32x4 w2 = *(const f32x4*)&sW2[(c + 2) * DD + c0];
      f32x4 w3 = *(const f32x4*)&sW2[(c + 3) * DD + c0];
      fma4(o0, s0[0], w0); fma4(o0, s0[1], w1); fma4(o0, s0[2], w2); fma4(o0, s0[3], w3);
      fma4(o1, s1[0], w0); fma4(o1, s1[1], w1); fma4(o1, s1[2], w2); fma4(o1, s1[3], w3);
    }
    size_t gr = (size_t)(bid * RPB + rg * 2) * DD + c0;
    uint2 p0, p1;
    p0.x = f2b(o0[0]) | (f2b(o0[1]) << 16);
    p0.y = f2b(o0[2]) | (f2b(o0[3]) << 16);
    p1.x = f2b(o1[0]) | (f2b(o1[1]) << 16);
    p1.y = f2b(o1[2]) | (f2b(o1[3]) << 16);
    *(uint2*)&xb16[gr] = p0;
    *(uint2*)&xb16[gr + DD] = p1;
    *(f32x4*)&pssum[rg * DD + c0] = o0 + o1;            // fp32 stats
    *(f32x4*)&pssq[rg * DD + c0] = o0 * o0 + o1 * o1;
  }
  __syncthreads();
  if (tid < DD) {
    float s = 0.f, q = 0.f;
#pragma unroll
    for (int g = 0; g < 8; ++g) { s += pssum[g * DD + tid]; q += pssq[g * DD + tid]; }
    atomicAdd(acc2 + tid * AST, s);
    atomicAdd(acc2 + (64 + tid) * AST, q);
  }
}

// fin: BN2 (no relu) from padded acc, bf16 h2 -> fp32 out
__global__ __launch_bounds__(256) void fin_kernel(
    const unsigned short* __restrict__ xb16, const float* __restrict__ gbn,
    const float* __restrict__ bbn, const float* __restrict__ acc2,
    float* __restrict__ outp) {
  __shared__ float sS2[DD], sB2[DD];
  int tid = threadIdx.x, bid = blockIdx.x;
  if (tid < 64) {
    float mean = acc2[tid * AST] * (1.f / RTOT);
    float var = fmaf(-mean, mean, acc2[(64 + tid) * AST] * (1.f / RTOT));
    float sc = gbn[tid] * rsqrtf(var + 1e-5f);
    sS2[tid] = sc;
    sB2[tid] = fmaf(-mean, sc, bbn[tid]);
  }
  __syncthreads();
  {
    int g = bid * 256 + tid;            // 4 elems per thread
    uint2 v = ((const uint2*)xb16)[g];
    int e0 = g * 4;
    int c0 = e0 & 63;
    f32x4 o;
    o[0] = fmaf(__uint_as_float(v.x << 16),        sS2[c0],     sB2[c0]);
    o[1] = fmaf(__uint_as_float(v.x & 0xFFFF0000u), sS2[c0 + 1], sB2[c0 + 1]);
    o[2] = fmaf(__uint_as_float(v.y << 16),        sS2[c0 + 2], sB2[c0 + 2]);
    o[3] = fmaf(__uint_as_float(v.y & 0xFFFF0000u), sS2[c0 + 3], sB2[c0 + 3]);
    *(f32x4*)&outp[e0] = o;
  }
}

extern "C" void kernel_launch(void* const* d_in, const int* in_sizes, int n_in,
                              void* d_out, int out_size, void* d_ws, size_t ws_size,
                              hipStream_t stream) {
  const float* fea  = (const float*)d_in[0];
  const float* adj  = (const float*)d_in[1];
  const float* encW = (const float*)d_in[2];
  const float* encb = (const float*)d_in[3];
  const float* bondW= (const float*)d_in[4];
  const float* eps  = (const float*)d_in[5];
  const float* W1   = (const float*)d_in[6];
  const float* b1   = (const float*)d_in[7];
  const float* g1   = (const float*)d_in[8];
  const float* be1  = (const float*)d_in[9];
  const float* W2   = (const float*)d_in[10];
  const float* b2   = (const float*)d_in[11];
  const float* gbn  = (const float*)d_in[12];
  const float* bbn  = (const float*)d_in[13];
  float* out = (float*)d_out;
  float* ws  = (float*)d_ws;

  unsigned short* xb16 = (unsigned short*)ws;              // 262144 bf16
  unsigned short* h1b  = (unsigned short*)(ws + 131072);   // 524288 bf16
  float* acc = ws + 131072 + 262144;   // 3 layers x 512 slots x AST floats

  enc_kernel<<<512, 256, 0, stream>>>(fea, encW, encb, xb16, acc);
  for (int l = 0; l < 3; ++l) {
    float* accl = acc + (size_t)l * 512 * AST;
    bc_kernel<<<GBC, 256, 0, stream>>>(
        adj, xb16, bondW + l * DD, eps + l, W1 + l * DD * D2, b1 + l * D2,
        l ? gbn + (l - 1) * DD : gbn, l ? bbn + (l - 1) * DD : bbn,
        l ? acc + (size_t)(l - 1) * 512 * AST + 256 * AST : acc,
        l > 0 ? 1 : 0, h1b, accl);
    d_kernel<<<GBD, 256, 0, stream>>>(h1b, W2 + l * D2 * DD, b2 + l * DD,
                                      g1 + l * D2, be1 + l * D2, xb16,
                                      accl, accl + 256 * AST);
  }
  fin_kernel<<<256, 256, 0, stream>>>(xb16, gbn + 2 * DD, bbn + 2 * DD,
                                      acc + (size_t)2 * 512 * AST + 256 * AST, out);
}